// Round 15
// baseline (2168.357 us; speedup 1.0000x reference)
//
#include <hip/hip_runtime.h>

// Seq2SeqWithAttention on MI355X. B=32, S=T=64, E=256, H=512, DH=1024, A=128, VT=32000.
// R15 = R14 + dedicated 256x128-tile logits GEMM (k_logits256): 2x MFMA:staging ratio,
// nM 16->8 halves worst-case Wbf re-read demand. Rest identical to R14.

using u16 = unsigned short;
using u32 = unsigned int;
using u64 = unsigned long long;
using f32x4 = __attribute__((ext_vector_type(4))) float;
using s16x8 = __attribute__((ext_vector_type(8))) short;
using u16x4 = __attribute__((ext_vector_type(4))) unsigned short;

__device__ __forceinline__ float sigm_(float x) { return 1.0f / (1.0f + expf(-x)); }
__device__ __forceinline__ float tanh_(float x) {
    float e = __expf(fminf(2.0f * x, 30.0f));
    return (e - 1.0f) / (e + 1.0f);
}

__device__ __forceinline__ u16 f2bf(float x) {
    u32 u = __float_as_uint(x);
    u += 0x7fffu + ((u >> 16) & 1u);
    return (u16)(u >> 16);
}
__device__ __forceinline__ u32 pk2(float a, float b) {
    return (u32)f2bf(a) | ((u32)f2bf(b) << 16);
}
__device__ __forceinline__ float bf2f(u16 v) {
    return __uint_as_float((u32)v << 16);
}

__device__ __forceinline__ void ast32(u32* p, u32 v) {
    __hip_atomic_store(p, v, __ATOMIC_RELAXED, __HIP_MEMORY_SCOPE_AGENT);
}

#define MFMA __builtin_amdgcn_mfma_f32_16x16x32_bf16

#define GLL(g, l) __builtin_amdgcn_global_load_lds( \
    (__attribute__((address_space(1))) void*)(g),   \
    (__attribute__((address_space(3))) void*)(l), 16, 0, 0)

// 8-line split handoff.
__device__ __forceinline__ void poll8(const int* go8) {
    if (threadIdx.x < 8) {
        const int* p = go8 + threadIdx.x * 16;
        while (__hip_atomic_load(p, __ATOMIC_RELAXED, __HIP_MEMORY_SCOPE_AGENT) == 0)
            __builtin_amdgcn_s_sleep(1);
    }
    __syncthreads();
    asm volatile("" ::: "memory");
}
__device__ __forceinline__ void arrive8(int* cnt8, int* go8, int line, int perline) {
    asm volatile("s_waitcnt vmcnt(0) lgkmcnt(0)" ::: "memory");
    __syncthreads();
    if (threadIdx.x == 0) {
        int old = __hip_atomic_fetch_add(cnt8 + line * 16, 1, __ATOMIC_RELAXED,
                                         __HIP_MEMORY_SCOPE_AGENT);
        if (old == perline - 1)
            __hip_atomic_store(go8 + line * 16, 1, __ATOMIC_RELAXED, __HIP_MEMORY_SCOPE_AGENT);
    }
}

// ---------------- zero ----------------
__global__ __launch_bounds__(256) void k_zero(float* __restrict__ p, int n) {
    int i = blockIdx.x * 256 + threadIdx.x;
    if (i < n) p[i] = 0.0f;
}

// ---------------- embedding gather -> bf16 [pos*32+b][256] ----------------
__global__ __launch_bounds__(256) void k_embed_bf(const int* __restrict__ tok,
                                                  const float* __restrict__ emb,
                                                  u16* __restrict__ outp) {
    int idx = blockIdx.x * 256 + threadIdx.x;   // 0..131071
    int r = idx >> 6, e4 = idx & 63;
    int outer = r >> 5, b = r & 31;
    int tk = tok[b * 64 + outer];
    f32x4 v = ((const f32x4*)emb)[(size_t)tk * 64 + e4];
    u32* o = (u32*)(outp + (size_t)r * 256 + (e4 << 2));
    o[0] = pk2(v.x, v.y); o[1] = pk2(v.z, v.w);
}

// ---------------- weight prep: gate-interleaved plain rows ----------------
__global__ __launch_bounds__(256) void k_prep_perm(
    const float* __restrict__ src, u16* __restrict__ dst,
    int J, int K4, int srcStride, int srcOff, int total)
{
    int idx = blockIdx.x * 256 + threadIdx.x;
    if (idx >= total) return;
    int n = idx / K4, kq = (idx - n * K4) << 2;
    int orig = (n & 3) * J + (n >> 2);
    f32x4 v = *(const f32x4*)(src + (size_t)orig * srcStride + srcOff + kq);
    u32* o = (u32*)(dst + (size_t)n * (K4 << 2) + kq);
    o[0] = pk2(v.x, v.y); o[1] = pk2(v.z, v.w);
}

// ---------------- enc Whh -> swizzled per-block LDS images ----------------
__global__ __launch_bounds__(256) void k_prep_ws(
    const float* __restrict__ W, u16* __restrict__ dst)
{
    int idx = blockIdx.x * 256 + threadIdx.x;   // 524288
    int n = idx >> 8, kp = idx & 255, k0 = kp << 1;
    int orig = (n & 3) * 512 + (n >> 2);
    const float* s = W + (size_t)orig * 512 + k0;
    int g = n >> 5, r = n & 31;
    int byteoff = (k0 << 1) ^ ((r & 7) << 4);
    *(u32*)((char*)dst + (size_t)g * 32768 + r * 1024 + byteoff) = pk2(s[0], s[1]);
}

// ---------------- generic bf16 MFMA GEMM (m97, 128x128, BK=32) ----------------
__global__ __launch_bounds__(256) void k_gemm_bf(
    const u16* __restrict__ A, const u16* __restrict__ B, int K,
    const float* __restrict__ b1, const float* __restrict__ b2, int biasJ,
    float* __restrict__ C, int ldc, int nM, int nN, int remapOut, int swz)
{
    __shared__ __align__(16) u16 As[128 * 32];
    __shared__ __align__(16) u16 Bs[128 * 32];
    int w = blockIdx.x;
    if (swz) { int cpx = (nM * nN) >> 3; w = (w & 7) * cpx + (w >> 3); }
    int bm = (w % nM) * 128, bn = (w / nM) * 128;
    int tid = threadIdx.x, wave = tid >> 6, lane = tid & 63;
    int wm = wave & 1, wn = wave >> 1;
    f32x4 acc[4][4] = {};

    int rA = wave * 32 + (lane >> 2);
    int cb2 = (lane & 3) * 16;
    const char* gA = (const char*)A + ((size_t)(bm + rA) * K) * 2 + cb2;
    const char* gB = (const char*)B + ((size_t)(bn + rA) * K) * 2 + cb2;
    size_t rowskip = (size_t)16 * K * 2;
    char* lA = (char*)As + wave * 2048;
    char* lB = (char*)Bs + wave * 2048;
    const u16* rdA = As + (wm * 64 + (lane & 15)) * 32 + (lane >> 4) * 8;
    const u16* rdB = Bs + (wn * 64 + (lane & 15)) * 32 + (lane >> 4) * 8;

    for (int k0 = 0; k0 < K; k0 += 32) {
        size_t kb = (size_t)k0 * 2;
        GLL(gA + kb, lA); GLL(gA + kb + rowskip, lA + 1024);
        GLL(gB + kb, lB); GLL(gB + kb + rowskip, lB + 1024);
        __syncthreads();
        s16x8 af[4], bfv[4];
#pragma unroll
        for (int m2 = 0; m2 < 4; ++m2) af[m2] = *(const s16x8*)(rdA + m2 * 512);
#pragma unroll
        for (int n2 = 0; n2 < 4; ++n2) bfv[n2] = *(const s16x8*)(rdB + n2 * 512);
#pragma unroll
        for (int m2 = 0; m2 < 4; ++m2)
#pragma unroll
            for (int n2 = 0; n2 < 4; ++n2)
                acc[m2][n2] = MFMA(af[m2], bfv[n2], acc[m2][n2], 0, 0, 0);
        __syncthreads();
    }

    int rbase = bm + wm * 64 + ((lane >> 4) << 2);
    int cbase = bn + wn * 64 + (lane & 15);
#pragma unroll
    for (int n2 = 0; n2 < 4; ++n2) {
        int col = cbase + n2 * 16;
        int bcol = biasJ ? ((col & 3) * biasJ + (col >> 2)) : col;
        float bias = (b1 ? b1[bcol] : 0.0f) + (b2 ? b2[bcol] : 0.0f);
#pragma unroll
        for (int m2 = 0; m2 < 4; ++m2) {
            f32x4 v = acc[m2][n2];
#pragma unroll
            for (int jj = 0; jj < 4; ++jj) {
                int row = rbase + m2 * 16 + jj;
                int orow = remapOut ? ((row & 31) * 64 + (row >> 5)) : row;
                C[(size_t)orow * ldc + col] = v[jj] + bias;
            }
        }
    }
}

// ---------------- logits GEMM: 256x128 tile, K=2048, remap + nt stores ----------------
// grid 2000 = nM(8) x nN(250), m-fastest, bijective XCD swizzle.
__global__ __launch_bounds__(256) void k_logits256(
    const u16* __restrict__ A, const u16* __restrict__ B,
    const float* __restrict__ bo, float* __restrict__ C)
{
    __shared__ __align__(16) u16 As[256 * 32];   // 16 KB
    __shared__ __align__(16) u16 Bs[128 * 32];   // 8 KB
    int w = blockIdx.x;
    w = (w & 7) * 250 + (w >> 3);                // 2000 % 8 == 0: bijective
    int bm = (w % 8) * 256, bn = (w / 8) * 128;
    int tid = threadIdx.x, wave = tid >> 6, lane = tid & 63;
    int wm = wave & 1, wn = wave >> 1;
    f32x4 acc[8][4] = {};

    int rA = wave * 64 + (lane >> 2);            // A: wave covers 64 rows (4 issues)
    int rB = wave * 32 + (lane >> 2);            // B: wave covers 32 rows (2 issues)
    int cb2 = (lane & 3) * 16;
    const char* gA = (const char*)A + ((size_t)(bm + rA) * 2048) * 2 + cb2;
    const char* gB = (const char*)B + ((size_t)(bn + rB) * 2048) * 2 + cb2;
    size_t rs = (size_t)16 * 2048 * 2;           // 16-row skip
    char* lA = (char*)As + wave * 4096;
    char* lB = (char*)Bs + wave * 2048;
    const u16* rdA = As + (wm * 128 + (lane & 15)) * 32 + (lane >> 4) * 8;
    const u16* rdB = Bs + (wn * 64 + (lane & 15)) * 32 + (lane >> 4) * 8;

    for (int k0 = 0; k0 < 2048; k0 += 32) {
        size_t kb = (size_t)k0 * 2;
        GLL(gA + kb, lA);               GLL(gA + kb + rs, lA + 1024);
        GLL(gA + kb + 2 * rs, lA + 2048); GLL(gA + kb + 3 * rs, lA + 3072);
        GLL(gB + kb, lB);               GLL(gB + kb + rs, lB + 1024);
        __syncthreads();
        s16x8 bfv[4];
#pragma unroll
        for (int n2 = 0; n2 < 4; ++n2) bfv[n2] = *(const s16x8*)(rdB + n2 * 512);
#pragma unroll
        for (int m2 = 0; m2 < 8; ++m2) {
            s16x8 af = *(const s16x8*)(rdA + m2 * 512);
#pragma unroll
            for (int n2 = 0; n2 < 4; ++n2)
                acc[m2][n2] = MFMA(af, bfv[n2], acc[m2][n2], 0, 0, 0);
        }
        __syncthreads();
    }

    int rbase = bm + wm * 128 + ((lane >> 4) << 2);
    int cbase = bn + wn * 64 + (lane & 15);
#pragma unroll
    for (int n2 = 0; n2 < 4; ++n2) {
        int col = cbase + n2 * 16;
        float bias = bo[col];
#pragma unroll
        for (int m2 = 0; m2 < 8; ++m2) {
            f32x4 v = acc[m2][n2];
#pragma unroll
            for (int jj = 0; jj < 4; ++jj) {
                int row = rbase + m2 * 16 + jj;
                int orow = (row & 31) * 64 + (row >> 5);   // (t*32+b) -> b*64+t
                __builtin_nontemporal_store(v[jj] + bias, C + (size_t)orow * 32000 + col);
            }
        }
    }
}

// ---------------- persistent encoder + prep workers ----------------
// 256 blocks: 0..127 = sync encoder; 128..255 = Wo/We/Wd casts + W2s swizzle prep.
__global__ __launch_bounds__(256, 1) void k_enc_persist(
    const u16* __restrict__ Wsf, const u16* __restrict__ Wsb,
    const float* __restrict__ Gfp, const float* __restrict__ Gbp,
    u16* __restrict__ henc,      // [65][2][32][512] bf16
    float* __restrict__ cfb,     // [dir][32][512] f32 (block-local)
    u16* __restrict__ encbf,     // [(b*64+t)][1024] bf16
    int* __restrict__ cnt8, int* __restrict__ go8,
    const float* __restrict__ Wo, u16* __restrict__ Wbf,
    const float* __restrict__ We, u16* __restrict__ We_bf,
    const float* __restrict__ Wd, u16* __restrict__ Wd_bf,
    const float* __restrict__ dWhh, const float* __restrict__ dWih,
    u16* __restrict__ W2s)
{
    __shared__ __align__(16) char smem[50176];
    int tid = threadIdx.x, lane = tid & 63, q = tid >> 6;

    if (blockIdx.x >= 128) {
        // ---------- prep workers ----------
        int gt = (blockIdx.x - 128) * 256 + tid;   // 0..32767
        for (int i = gt; i < 8192000; i += 32768) {     // Wo cast (32000 x 2048)
            const f32x4* p = (const f32x4*)Wo + (size_t)i * 2;
            f32x4 a = p[0], c = p[1];
            u32* o = (u32*)(Wbf + (size_t)i * 8);
            o[0] = pk2(a.x, a.y); o[1] = pk2(a.z, a.w);
            o[2] = pk2(c.x, c.y); o[3] = pk2(c.z, c.w);
        }
        if (gt < 16384) {                               // We / Wd casts
            const f32x4* p = (const f32x4*)We + (size_t)gt * 2;
            f32x4 a = p[0], c = p[1];
            u32* o = (u32*)(We_bf + (size_t)gt * 8);
            o[0] = pk2(a.x, a.y); o[1] = pk2(a.z, a.w);
            o[2] = pk2(c.x, c.y); o[3] = pk2(c.z, c.w);
            const f32x4* p2 = (const f32x4*)Wd + (size_t)gt * 2;
            f32x4 a2 = p2[0], c2 = p2[1];
            u32* o2 = (u32*)(Wd_bf + (size_t)gt * 8);
            o2[0] = pk2(a2.x, a2.y); o2[1] = pk2(a2.z, a2.w);
            o2[2] = pk2(c2.x, c2.y); o2[3] = pk2(c2.z, c2.w);
        }
        for (int i = gt; i < 4194304; i += 32768) {     // dec W2 swizzled images
            int n = i >> 10, kp = i & 1023, k0 = kp << 1;
            int orig = (n & 3) * 1024 + (n >> 2);
            const float* s = (k0 < 1024) ? (dWhh + (size_t)orig * 1024 + k0)
                                         : (dWih + (size_t)orig * 1280 + 256 + (k0 - 1024));
            int g2 = n >> 5, r = n & 31;
            int byteoff = (k0 << 1) ^ ((r & 7) << 4);
            *(u32*)((char*)W2s + (size_t)g2 * 131072 + r * 4096 + byteoff) = pk2(s[0], s[1]);
        }
        return;
    }

    // ---------- sync encoder (R9) ----------
    int dir = blockIdx.x >> 6, g = blockIdx.x & 63;
    const char* wsrc = (const char*)(dir ? Wsb : Wsf) + (size_t)g * 32768;
#pragma unroll
    for (int it = 0; it < 8; ++it)
        GLL(wsrc + it * 4096 + tid * 16, smem + it * 4096 + tid * 16);
    __syncthreads();

    float* sacc = (float*)(smem + 32768);   // [4][32][33]
    u16* hst = (u16*)(smem + 49664);        // [32][8]
    const float* Gp = dir ? Gbp : Gfp;
    float* cB = cfb + dir * 16384;
    int lr = lane & 15, lk = (lane >> 4) << 3;
    int bb = tid & 31, jl = tid >> 5;
    int n0 = g * 32, j = g * 8 + jl;

    for (int s = 0; s < 64; ++s) {
        if (s) poll8(go8 + s * 128);
        int t = dir ? (63 - s) : s;
        f32x4 p4 = *(const f32x4*)(Gp + ((size_t)(t * 32 + bb)) * 2048 + n0 + (jl << 2));
        const u16* hA = henc + (size_t)s * 32768 + dir * 16384;
        s16x8 afr[8];
#pragma unroll
        for (int it = 0; it < 4; ++it) {
            int ke = q * 128 + it * 32 + lk;
            afr[2 * it]     = *(const s16x8*)(hA + lr * 512 + ke);
            afr[2 * it + 1] = *(const s16x8*)(hA + (lr + 16) * 512 + ke);
        }
        f32x4 acc00 = {}, acc01 = {}, acc10 = {}, acc11 = {};
#pragma unroll
        for (int it = 0; it < 4; ++it) {
            int ke = q * 128 + it * 32 + lk;
            int kb = ke << 1;
            s16x8 b0 = *(const s16x8*)(smem + lr * 1024 + (kb ^ ((lr & 7) << 4)));
            int r1 = lr + 16;
            s16x8 b1 = *(const s16x8*)(smem + r1 * 1024 + (kb ^ ((r1 & 7) << 4)));
            acc00 = MFMA(afr[2 * it], b0, acc00, 0, 0, 0);
            acc01 = MFMA(afr[2 * it], b1, acc01, 0, 0, 0);
            acc10 = MFMA(afr[2 * it + 1], b0, acc10, 0, 0, 0);
            acc11 = MFMA(afr[2 * it + 1], b1, acc11, 0, 0, 0);
        }
        int rw = (lane >> 4) << 2;
#pragma unroll
        for (int rr = 0; rr < 4; ++rr) {
            sacc[q * 1056 + (rw + rr) * 33 + lr]        = acc00[rr];
            sacc[q * 1056 + (rw + rr) * 33 + 16 + lr]   = acc01[rr];
            sacc[q * 1056 + (16 + rw + rr) * 33 + lr]      = acc10[rr];
            sacc[q * 1056 + (16 + rw + rr) * 33 + 16 + lr] = acc11[rr];
        }
        __syncthreads();
        {
            int c4 = jl << 2;
            float gi = 0, gf = 0, gg = 0, go2 = 0;
#pragma unroll
            for (int q2 = 0; q2 < 4; ++q2) {
                const float* sp = sacc + q2 * 1056 + bb * 33 + c4;
                gi += sp[0]; gf += sp[1]; gg += sp[2]; go2 += sp[3];
            }
            gi += p4.x; gf += p4.y; gg += p4.z; go2 += p4.w;
            float* cp = cB + bb * 512 + j;
            float cn = sigm_(gf) * cp[0] + sigm_(gi) * tanhf(gg);
            cp[0] = cn;
            float h = sigm_(go2) * tanhf(cn);
            u16 h16 = f2bf(h);
            encbf[((size_t)(bb * 64 + t)) * 1024 + dir * 512 + j] = h16;
            hst[bb * 8 + jl] = h16;
        }
        __syncthreads();
        if (tid < 128) {
            int bb2 = tid >> 2, p2 = tid & 3;
            u32 wv = (u32)hst[bb2 * 8 + 2 * p2] | ((u32)hst[bb2 * 8 + 2 * p2 + 1] << 16);
            ast32((u32*)(henc + (size_t)(s + 1) * 32768 + dir * 16384) + bb2 * 256 + g * 4 + p2, wv);
        }
        arrive8(cnt8 + (s + 1) * 128, go8 + (s + 1) * 128, blockIdx.x & 7, 16);
    }
}

// ---------------- decoder init ----------------
__global__ __launch_bounds__(256) void k_dec_init(
    const u16* __restrict__ henc, const float* __restrict__ cfb,
    u16* __restrict__ hcarr, float* __restrict__ cd)
{
    int idx = blockIdx.x * 256 + threadIdx.x;   // 0..32767
    int b = idx >> 10, j = idx & 1023;
    int dir = (j >> 9), jj = j & 511;
    hcarr[b * 2048 + j] = henc[(size_t)64 * 32768 + dir * 16384 + b * 512 + jj];
    cd[b * 1024 + j] = cfb[dir * 16384 + b * 512 + jj];
}

// ---------------- persistent decoder (R9): split-line handoffs ----------------
__global__ __launch_bounds__(256, 1) void k_dec_persist(
    const u16* __restrict__ W2s, const u16* __restrict__ encbf,
    const float* __restrict__ Prep,
    const u16* __restrict__ Wd_bf, const float* __restrict__ bd,
    const float* __restrict__ eproj, const float* __restrict__ v_att,
    const float* __restrict__ bv,
    u16* __restrict__ hcarr, float* __restrict__ cd, u16* __restrict__ Abf,
    int* __restrict__ hCnt8, int* __restrict__ goH8,
    int* __restrict__ ctxCnt8, int* __restrict__ goCtx8)
{
    __shared__ __align__(16) char smem[148480];
    int blk = blockIdx.x, tid = threadIdx.x, lane = tid & 63, q = tid >> 6;
    bool isgate = blk < 128;
    {
        const char* src = isgate ? ((const char*)W2s + (size_t)blk * 131072)
                                 : ((const char*)encbf + (size_t)(blk - 128) * 131072);
#pragma unroll
        for (int it = 0; it < 32; ++it)
            GLL(src + it * 4096 + tid * 16, smem + it * 4096 + tid * 16);
    }
    __syncthreads();

    float* sacc = (float*)(smem + 131072);  // gates: [4][32][33]
    u16* hst    = (u16*)(smem + 147968);    // gates: [32][8]
    float* hsh  = (float*)(smem + 131072);  // attn: h f32 [1024]
    float* red  = (float*)(smem + 135168);  // attn: [256]
    float* dp   = (float*)(smem + 136192);  // attn: [128]
    float* sc   = (float*)(smem + 136704);  // attn: [64]

    int lr = lane & 15, lk = (lane >> 4) << 3;
    int bb = tid & 31, jl = tid >> 5;
    int n0 = blk * 32, j = blk * 8 + jl;
    int b = blk - 128;

    for (int t = 0; t < 64; ++t) {
        if (t) poll8(goH8 + t * 128);
        const u16* hcT = hcarr + (size_t)t * 65536;
        if (isgate) {
            f32x4 p4 = *(const f32x4*)(Prep + ((size_t)(t * 32 + bb)) * 4096 + n0 + (jl << 2));
            // ---- phase A: Whh · h_t (k in [0,1024)) ----
            s16x8 afr[16];
#pragma unroll
            for (int it = 0; it < 8; ++it) {
                int ke = q * 256 + it * 32 + lk;
                afr[2 * it]     = *(const s16x8*)(hcT + lr * 2048 + ke);
                afr[2 * it + 1] = *(const s16x8*)(hcT + (lr + 16) * 2048 + ke);
            }
            f32x4 acc00 = {}, acc01 = {}, acc10 = {}, acc11 = {};
#pragma unroll
            for (int it = 0; it < 8; ++it) {
                int ke = q * 256 + it * 32 + lk;
                int kb = ke << 1;
                s16x8 b0 = *(const s16x8*)(smem + lr * 4096 + (kb ^ ((lr & 7) << 4)));
                int r1 = lr + 16;
                s16x8 b1 = *(const s16x8*)(smem + r1 * 4096 + (kb ^ ((r1 & 7) << 4)));
                acc00 = MFMA(afr[2 * it], b0, acc00, 0, 0, 0);
                acc01 = MFMA(afr[2 * it], b1, acc01, 0, 0, 0);
                acc10 = MFMA(afr[2 * it + 1], b0, acc10, 0, 0, 0);
                acc11 = MFMA(afr[2 * it + 1], b1, acc11, 0, 0, 0);
            }
            // ---- wait for ctx_t ----
            poll8(goCtx8 + t * 128);
            // ---- phase B: Wctx · ctx_t (k in [1024,2048)) ----
#pragma unroll
            for (int it = 0; it < 8; ++it) {
                int ke = 1024 + q * 256 + it * 32 + lk;
                afr[2 * it]     = *(const s16x8*)(hcT + lr * 2048 + ke);
                afr[2 * it + 1] = *(const s16x8*)(hcT + (lr + 16) * 2048 + ke);
            }
#pragma unroll
            for (int it = 0; it < 8; ++it) {
                int ke = 1024 + q * 256 + it * 32 + lk;
                int kb = ke << 1;
                s16x8 b0 = *(const s16x8*)(smem + lr * 4096 + (kb ^ ((lr & 7) << 4)));
                int r1 = lr + 16;
                s16x8 b1 = *(const s16x8*)(smem + r1 * 4096 + (kb ^ ((r1 & 7) << 4)));
                acc00 = MFMA(afr[2 * it], b0, acc00, 0, 0, 0);
                acc01 = MFMA(afr[2 * it], b1, acc01, 0, 0, 0);
                acc10 = MFMA(afr[2 * it + 1], b0, acc10, 0, 0, 0);
                acc11 = MFMA(afr[2 * it + 1], b1, acc11, 0, 0, 0);
            }
            int rw = (lane >> 4) << 2;
#pragma unroll
            for (int rr = 0; rr < 4; ++rr) {
                sacc[q * 1056 + (rw + rr) * 33 + lr]        = acc00[rr];
                sacc[q * 1056 + (rw + rr) * 33 + 16 + lr]   = acc01[rr];
                sacc[q * 1056 + (16 + rw + rr) * 33 + lr]      = acc10[rr];
                sacc[q * 1056 + (16 + rw + rr) * 33 + 16 + lr] = acc11[rr];
            }
            __syncthreads();
            {
                int c4 = jl << 2;
                float gi = 0, gf = 0, gg = 0, go2 = 0;
#pragma unroll
                for (int q2 = 0; q2 < 4; ++q2) {
                    const float* sp = sacc + q2 * 1056 + bb * 33 + c4;
                    gi += sp[0]; gf += sp[1]; gg += sp[2]; go2 += sp[3];
                }
                gi += p4.x; gf += p4.y; gg += p4.z; go2 += p4.w;
                int ci = bb * 1024 + j;
                float cn = sigm_(gf) * cd[ci] + sigm_(gi) * tanhf(gg);
                cd[ci] = cn;
                float h = sigm_(go2) * tanhf(cn);
                u16 h16 = f2bf(h);
                Abf[((size_t)(t * 32 + bb)) * 2048 + j] = h16;
                hst[bb * 8 + jl] = h16;
            }
            __syncthreads();
            if (tid < 128) {
                int bb2 = tid >> 2, p2 = tid & 3;
                u32 wv = (u32)hst[bb2 * 8 + 2 * p2] | ((u32)hst[bb2 * 8 + 2 * p2 + 1] << 16);
                ast32((u32*)(hcarr + (size_t)(t + 1) * 65536) + bb2 * 1024 + blk * 4 + p2, wv);
            }
            arrive8(hCnt8 + (t + 1) * 128, goH8 + (t + 1) * 128, blk & 7, 16);
        } else {
            // ---- attention for batch row b ----
            {
                u16x4 hv = *(const u16x4*)(hcT + b * 2048 + (tid << 2));
                hsh[(tid << 2) + 0] = bf2f(hv.x);
                hsh[(tid << 2) + 1] = bf2f(hv.y);
                hsh[(tid << 2) + 2] = bf2f(hv.z);
                hsh[(tid << 2) + 3] = bf2f(hv.w);
            }
            __syncthreads();
            {
                int a = tid & 127, half = tid >> 7;
                const u16* wr = Wd_bf + ((size_t)a << 10) + (half << 9);
                const float* hh = hsh + (half << 9);
                float s0 = 0, s1 = 0, s2 = 0, s3 = 0;
#pragma unroll 4
                for (int k = 0; k < 512; k += 32) {
                    s16x8 w0 = *(const s16x8*)(wr + k);
                    s16x8 w1 = *(const s16x8*)(wr + k + 8);
                    s16x8 w2 = *(const s16x8*)(wr + k + 16);
                    s16x8 w3 = *(const s16x8*)(wr + k + 24);
#pragma unroll
                    for (int e = 0; e < 8; ++e) {
                        s0 += bf2f((u16)w0[e]) * hh[k + e];
                        s1 += bf2f((u16)w1[e]) * hh[k + 8 + e];
                        s2 += bf2f((u16)w2[e]) * hh[k + 16 + e];
                        s3 += bf2f((u16)w3[e]) * hh[k + 24 + e];
                    }
                }
                red[tid] = (s0 + s1) + (s2 + s3);
            }
            __syncthreads();
            if (tid < 128) dp[tid] = red[tid] + red[tid + 128] + bd[tid];
            __syncthreads();
            {
                int si = tid >> 2, qq = tid & 3;
                const float* ep = eproj + ((size_t)(b * 64 + si)) * 128 + qq * 32;
                float s = 0.0f;
#pragma unroll 8
                for (int a2 = 0; a2 < 32; ++a2)
                    s += v_att[qq * 32 + a2] * tanh_(dp[qq * 32 + a2] + ep[a2]);
                red[tid] = s;
            }
            __syncthreads();
            if (tid < 64) {
                float x = red[tid * 4] + red[tid * 4 + 1] + red[tid * 4 + 2] + red[tid * 4 + 3] + bv[0];
                float mx = x;
#pragma unroll
                for (int off = 32; off; off >>= 1) mx = fmaxf(mx, __shfl_xor(mx, off));
                float e = __expf(x - mx), ss = e;
#pragma unroll
                for (int off = 32; off; off >>= 1) ss += __shfl_xor(ss, off);
                sc[tid] = e / ss;
            }
            __syncthreads();
            u32 cw0, cw1;
            {
                const u16* eL = (const u16*)smem;
                int c0i = tid << 2;
                float c0 = 0, c1 = 0, c2 = 0, c3 = 0;
                for (int s2 = 0; s2 < 64; ++s2) {
                    float wgt = sc[s2];
                    u16x4 rp = *(const u16x4*)(eL + s2 * 1024 + c0i);
                    c0 += wgt * bf2f(rp.x); c1 += wgt * bf2f(rp.y);
                    c2 += wgt * bf2f(rp.z); c3 += wgt * bf2f(rp.w);
                }
                cw0 = pk2(c0, c1); cw1 = pk2(c2, c3);
                u32* hw = (u32*)hcT + b * 1024 + 512 + (tid << 1);
                ast32(hw, cw0); ast32(hw + 1, cw1);
            }
            arrive8(ctxCnt8 + t * 128, goCtx8 + t * 128, blk & 7, 4);
            {   // Abf ctx copy off the critical path
                u32* aw = (u32*)(Abf + ((size_t)(t * 32 + b)) * 2048 + 1024 + (tid << 2));
                aw[0] = cw0; aw[1] = cw1;
            }
        }
    }
}

// ---------------- host ----------------
extern "C" void kernel_launch(void* const* d_in, const int* in_sizes, int n_in,
                              void* d_out, int out_size, void* d_ws, size_t ws_size,
                              hipStream_t stream)
{
    (void)in_sizes; (void)n_in; (void)out_size; (void)ws_size;
    const int*   src     = (const int*)d_in[0];
    const int*   tgt     = (const int*)d_in[1];
    const float* enc_emb = (const float*)d_in[2];
    const float* eWih_f  = (const float*)d_in[3];
    const float* eWhh_f  = (const float*)d_in[4];
    const float* ebih_f  = (const float*)d_in[5];
    const float* ebhh_f  = (const float*)d_in[6];
    const float* eWih_b  = (const float*)d_in[7];
    const float* eWhh_b  = (const float*)d_in[8];
    const float* ebih_b  = (const float*)d_in[9];
    const float* ebhh_b  = (const float*)d_in[10];
    const float* dec_emb = (const float*)d_in[11];
    const float* Wd      = (const float*)d_in[12];
    const float* bd      = (const float*)d_in[13];
    const float* We      = (const float*)d_in[14];
    const float* be      = (const float*)d_in[15];
    const float* v_att   = (const float*)d_in[16];
    const float* bv      = (const float*)d_in[17];
    const float* dWih    = (const float*)d_in[18];
    const float* dWhh    = (const float*)d_in[19];
    const float* dbih    = (const float*)d_in[20];
    const float* dbhh    = (const float*)d_in[21];
    const float* Wo      = (const float*)d_in[22];
    const float* bo      = (const float*)d_in[23];
    float* out = (float*)d_out;

    char* wp = (char*)d_ws;
    auto alloc = [&](size_t nbytes) -> void* {
        void* p = (void*)wp;
        wp += (nbytes + 255) & ~(size_t)255;
        return p;
    };
    u16*   Xe_bf = (u16*)alloc(2048u * 256 * 2);
    u16*   Ed_bf = (u16*)alloc(2048u * 256 * 2);
    float* Gf_p  = (float*)alloc(2048u * 2048 * 4);
    float* Gb_p  = (float*)alloc(2048u * 2048 * 4);
    float* Pre_p = (float*)alloc(2048u * 4096 * 4);
    float* zr    = (float*)alloc(329728u);             // cfb | sync arrays
    float* cfb   = zr;                                 // 131072 B
    char*  sy    = (char*)zr + 131072;
    int*   cntE8 = (int*)(sy);                          // 65*512 B
    int*   goE8  = (int*)(sy + 33280);
    int*   hCnt8 = (int*)(sy + 66560);
    int*   goH8  = (int*)(sy + 99840);
    int*   ctxC8 = (int*)(sy + 133120);                 // 64*512 B
    int*   goX8  = (int*)(sy + 165888);
    u16*   henc  = (u16*)alloc(65u * 32768 * 2);       // per-step enc h
    u16*   hcarr = (u16*)alloc(65u * 65536 * 2);       // per-step dec h|ctx
    u16*   encbf = (u16*)alloc(2048u * 1024 * 2);
    float* eproj = (float*)alloc(2048u * 128 * 4);
    float* cd    = (float*)alloc(32768u * 4);
    u16*   Abf   = (u16*)alloc(2048u * 2048 * 2);
    u16*   Wbf   = (u16*)alloc(32000u * 2048 * 2);
    u16*   W2s   = (u16*)alloc(4096u * 2048 * 2);
    u16*   Wsf   = (u16*)alloc(2048u * 512 * 2);
    u16*   Wsb   = (u16*)alloc(2048u * 512 * 2);
    u16*   Wembf = (u16*)alloc(2048u * 256 * 2);
    u16*   Wembb = (u16*)alloc(2048u * 256 * 2);
    u16*   Wembd = (u16*)alloc(4096u * 256 * 2);
    u16*   We_bf = (u16*)alloc(128u * 1024 * 2);
    u16*   Wd_bf = (u16*)alloc(128u * 1024 * 2);

    // zero cfb + sync (329728 B = 82432 f32), henc step-0
    k_zero<<<322, 256, 0, stream>>>(zr, 82432);
    k_zero<<<64, 256, 0, stream>>>((float*)henc, 16384);

    // weight prep needed BEFORE encoder (rest is fused into encoder prep workers)
    k_prep_perm<<<512, 256, 0, stream>>>(eWih_f, Wembf, 512, 64, 256, 0, 131072);
    k_prep_perm<<<512, 256, 0, stream>>>(eWih_b, Wembb, 512, 64, 256, 0, 131072);
    k_prep_perm<<<1024, 256, 0, stream>>>(dWih, Wembd, 1024, 64, 1280, 0, 262144);
    k_prep_ws<<<2048, 256, 0, stream>>>(eWhh_f, Wsf);
    k_prep_ws<<<2048, 256, 0, stream>>>(eWhh_b, Wsb);

    k_embed_bf<<<512, 256, 0, stream>>>(src, enc_emb, Xe_bf);
    k_embed_bf<<<512, 256, 0, stream>>>(tgt, dec_emb, Ed_bf);

    // input projections (gate-interleaved outputs, biases folded)
    k_gemm_bf<<<256, 256, 0, stream>>>(Xe_bf, Wembf, 256, ebih_f, ebhh_f, 512,
                                       Gf_p, 2048, 16, 16, 0, 1);
    k_gemm_bf<<<256, 256, 0, stream>>>(Xe_bf, Wembb, 256, ebih_b, ebhh_b, 512,
                                       Gb_p, 2048, 16, 16, 0, 1);
    k_gemm_bf<<<512, 256, 0, stream>>>(Ed_bf, Wembd, 256, dbih, dbhh, 1024,
                                       Pre_p, 4096, 16, 32, 0, 1);

    // persistent encoder (128 sync) + prep workers (128): Wo/We/Wd casts + W2s
    k_enc_persist<<<256, 256, 0, stream>>>(Wsf, Wsb, Gf_p, Gb_p, henc, cfb, encbf,
                                           cntE8, goE8,
                                           Wo, Wbf, We, We_bf, Wd, Wd_bf,
                                           dWhh, dWih, W2s);

    // enc_proj + decoder init
    k_gemm_bf<<<16, 256, 0, stream>>>(encbf, We_bf, 1024, be, nullptr, 0,
                                      eproj, 128, 16, 1, 0, 1);
    k_dec_init<<<128, 256, 0, stream>>>(henc, cfb, hcarr, cd);

    // persistent decoder (R9, 160 blocks)
    k_dec_persist<<<160, 256, 0, stream>>>(W2s, encbf, Pre_p, Wd_bf, bd, eproj,
                                           v_att, bv, hcarr, cd, Abf,
                                           hCnt8, goH8, ctxC8, goX8);

    // logits: 256x128-tile GEMM, [2048,2048] @ [32000,2048]^T, remap, nt stores
    k_logits256<<<2000, 256, 0, stream>>>(Abf, Wbf, bo, out);
}

// Round 16
// 1945.395 us; speedup vs baseline: 1.1146x; 1.1146x over previous
//
#include <hip/hip_runtime.h>

// Seq2SeqWithAttention on MI355X. B=32, S=T=64, E=256, H=512, DH=1024, A=128, VT=32000.
// R16 = R14 exact revert (best measured: 1961us). R15's 256x128 logits tile regressed
// (VGPR/occupancy cliff); 128x128 m97 logits restored. Components: R9 decoder
// (split-line handoffs), R12 encoder+prep-workers, standalone 128^2 logits w/ nt stores.

using u16 = unsigned short;
using u32 = unsigned int;
using u64 = unsigned long long;
using f32x4 = __attribute__((ext_vector_type(4))) float;
using s16x8 = __attribute__((ext_vector_type(8))) short;
using u16x4 = __attribute__((ext_vector_type(4))) unsigned short;

__device__ __forceinline__ float sigm_(float x) { return 1.0f / (1.0f + expf(-x)); }
__device__ __forceinline__ float tanh_(float x) {
    float e = __expf(fminf(2.0f * x, 30.0f));
    return (e - 1.0f) / (e + 1.0f);
}

__device__ __forceinline__ u16 f2bf(float x) {
    u32 u = __float_as_uint(x);
    u += 0x7fffu + ((u >> 16) & 1u);
    return (u16)(u >> 16);
}
__device__ __forceinline__ u32 pk2(float a, float b) {
    return (u32)f2bf(a) | ((u32)f2bf(b) << 16);
}
__device__ __forceinline__ float bf2f(u16 v) {
    return __uint_as_float((u32)v << 16);
}

__device__ __forceinline__ void ast32(u32* p, u32 v) {
    __hip_atomic_store(p, v, __ATOMIC_RELAXED, __HIP_MEMORY_SCOPE_AGENT);
}

#define MFMA __builtin_amdgcn_mfma_f32_16x16x32_bf16

#define GLL(g, l) __builtin_amdgcn_global_load_lds( \
    (__attribute__((address_space(1))) void*)(g),   \
    (__attribute__((address_space(3))) void*)(l), 16, 0, 0)

// 8-line split handoff.
__device__ __forceinline__ void poll8(const int* go8) {
    if (threadIdx.x < 8) {
        const int* p = go8 + threadIdx.x * 16;
        while (__hip_atomic_load(p, __ATOMIC_RELAXED, __HIP_MEMORY_SCOPE_AGENT) == 0)
            __builtin_amdgcn_s_sleep(1);
    }
    __syncthreads();
    asm volatile("" ::: "memory");
}
__device__ __forceinline__ void arrive8(int* cnt8, int* go8, int line, int perline) {
    asm volatile("s_waitcnt vmcnt(0) lgkmcnt(0)" ::: "memory");
    __syncthreads();
    if (threadIdx.x == 0) {
        int old = __hip_atomic_fetch_add(cnt8 + line * 16, 1, __ATOMIC_RELAXED,
                                         __HIP_MEMORY_SCOPE_AGENT);
        if (old == perline - 1)
            __hip_atomic_store(go8 + line * 16, 1, __ATOMIC_RELAXED, __HIP_MEMORY_SCOPE_AGENT);
    }
}

// ---------------- zero ----------------
__global__ __launch_bounds__(256) void k_zero(float* __restrict__ p, int n) {
    int i = blockIdx.x * 256 + threadIdx.x;
    if (i < n) p[i] = 0.0f;
}

// ---------------- embedding gather -> bf16 [pos*32+b][256] ----------------
__global__ __launch_bounds__(256) void k_embed_bf(const int* __restrict__ tok,
                                                  const float* __restrict__ emb,
                                                  u16* __restrict__ outp) {
    int idx = blockIdx.x * 256 + threadIdx.x;   // 0..131071
    int r = idx >> 6, e4 = idx & 63;
    int outer = r >> 5, b = r & 31;
    int tk = tok[b * 64 + outer];
    f32x4 v = ((const f32x4*)emb)[(size_t)tk * 64 + e4];
    u32* o = (u32*)(outp + (size_t)r * 256 + (e4 << 2));
    o[0] = pk2(v.x, v.y); o[1] = pk2(v.z, v.w);
}

// ---------------- weight prep: gate-interleaved plain rows ----------------
__global__ __launch_bounds__(256) void k_prep_perm(
    const float* __restrict__ src, u16* __restrict__ dst,
    int J, int K4, int srcStride, int srcOff, int total)
{
    int idx = blockIdx.x * 256 + threadIdx.x;
    if (idx >= total) return;
    int n = idx / K4, kq = (idx - n * K4) << 2;
    int orig = (n & 3) * J + (n >> 2);
    f32x4 v = *(const f32x4*)(src + (size_t)orig * srcStride + srcOff + kq);
    u32* o = (u32*)(dst + (size_t)n * (K4 << 2) + kq);
    o[0] = pk2(v.x, v.y); o[1] = pk2(v.z, v.w);
}

// ---------------- enc Whh -> swizzled per-block LDS images ----------------
__global__ __launch_bounds__(256) void k_prep_ws(
    const float* __restrict__ W, u16* __restrict__ dst)
{
    int idx = blockIdx.x * 256 + threadIdx.x;   // 524288
    int n = idx >> 8, kp = idx & 255, k0 = kp << 1;
    int orig = (n & 3) * 512 + (n >> 2);
    const float* s = W + (size_t)orig * 512 + k0;
    int g = n >> 5, r = n & 31;
    int byteoff = (k0 << 1) ^ ((r & 7) << 4);
    *(u32*)((char*)dst + (size_t)g * 32768 + r * 1024 + byteoff) = pk2(s[0], s[1]);
}

// ---------------- generic bf16 MFMA GEMM (m97 structure, 128x128 tile, BK=32) ----------------
// ntStore=1: nontemporal C writes (write-once output streams).
__global__ __launch_bounds__(256) void k_gemm_bf(
    const u16* __restrict__ A, const u16* __restrict__ B, int K,
    const float* __restrict__ b1, const float* __restrict__ b2, int biasJ,
    float* __restrict__ C, int ldc, int nM, int nN, int remapOut, int swz, int ntStore)
{
    __shared__ __align__(16) u16 As[128 * 32];
    __shared__ __align__(16) u16 Bs[128 * 32];
    int w = blockIdx.x;
    if (swz) { int cpx = (nM * nN) >> 3; w = (w & 7) * cpx + (w >> 3); }
    int bm = (w % nM) * 128, bn = (w / nM) * 128;
    int tid = threadIdx.x, wave = tid >> 6, lane = tid & 63;
    int wm = wave & 1, wn = wave >> 1;
    f32x4 acc[4][4] = {};

    int rA = wave * 32 + (lane >> 2);
    int cb2 = (lane & 3) * 16;
    const char* gA = (const char*)A + ((size_t)(bm + rA) * K) * 2 + cb2;
    const char* gB = (const char*)B + ((size_t)(bn + rA) * K) * 2 + cb2;
    size_t rowskip = (size_t)16 * K * 2;
    char* lA = (char*)As + wave * 2048;
    char* lB = (char*)Bs + wave * 2048;
    const u16* rdA = As + (wm * 64 + (lane & 15)) * 32 + (lane >> 4) * 8;
    const u16* rdB = Bs + (wn * 64 + (lane & 15)) * 32 + (lane >> 4) * 8;

    for (int k0 = 0; k0 < K; k0 += 32) {
        size_t kb = (size_t)k0 * 2;
        GLL(gA + kb, lA); GLL(gA + kb + rowskip, lA + 1024);
        GLL(gB + kb, lB); GLL(gB + kb + rowskip, lB + 1024);
        __syncthreads();
        s16x8 af[4], bfv[4];
#pragma unroll
        for (int m2 = 0; m2 < 4; ++m2) af[m2] = *(const s16x8*)(rdA + m2 * 512);
#pragma unroll
        for (int n2 = 0; n2 < 4; ++n2) bfv[n2] = *(const s16x8*)(rdB + n2 * 512);
#pragma unroll
        for (int m2 = 0; m2 < 4; ++m2)
#pragma unroll
            for (int n2 = 0; n2 < 4; ++n2)
                acc[m2][n2] = MFMA(af[m2], bfv[n2], acc[m2][n2], 0, 0, 0);
        __syncthreads();
    }

    int rbase = bm + wm * 64 + ((lane >> 4) << 2);
    int cbase = bn + wn * 64 + (lane & 15);
#pragma unroll
    for (int n2 = 0; n2 < 4; ++n2) {
        int col = cbase + n2 * 16;
        int bcol = biasJ ? ((col & 3) * biasJ + (col >> 2)) : col;
        float bias = (b1 ? b1[bcol] : 0.0f) + (b2 ? b2[bcol] : 0.0f);
#pragma unroll
        for (int m2 = 0; m2 < 4; ++m2) {
            f32x4 v = acc[m2][n2];
#pragma unroll
            for (int jj = 0; jj < 4; ++jj) {
                int row = rbase + m2 * 16 + jj;
                int orow = remapOut ? ((row & 31) * 64 + (row >> 5)) : row;
                float val = v[jj] + bias;
                float* cp = C + (size_t)orow * ldc + col;
                if (ntStore) __builtin_nontemporal_store(val, cp);
                else *cp = val;
            }
        }
    }
}

// ---------------- persistent encoder + prep workers ----------------
// 256 blocks: 0..127 = sync encoder (R9 logic); 128..255 = workers doing
// Wo/We/Wd bf16 casts + W2s swizzle prep (all consumed after this kernel).
__global__ __launch_bounds__(256, 1) void k_enc_persist(
    const u16* __restrict__ Wsf, const u16* __restrict__ Wsb,
    const float* __restrict__ Gfp, const float* __restrict__ Gbp,
    u16* __restrict__ henc,      // [65][2][32][512] bf16
    float* __restrict__ cfb,     // [dir][32][512] f32 (block-local)
    u16* __restrict__ encbf,     // [(b*64+t)][1024] bf16
    int* __restrict__ cnt8, int* __restrict__ go8,
    const float* __restrict__ Wo, u16* __restrict__ Wbf,
    const float* __restrict__ We, u16* __restrict__ We_bf,
    const float* __restrict__ Wd, u16* __restrict__ Wd_bf,
    const float* __restrict__ dWhh, const float* __restrict__ dWih,
    u16* __restrict__ W2s)
{
    __shared__ __align__(16) char smem[50176];
    int tid = threadIdx.x, lane = tid & 63, q = tid >> 6;

    if (blockIdx.x >= 128) {
        // ---------- prep workers ----------
        int gt = (blockIdx.x - 128) * 256 + tid;   // 0..32767
        // Wo cast: 8,192,000 units of 8 f32 (32000 x 2048)
        for (int i = gt; i < 8192000; i += 32768) {
            const f32x4* p = (const f32x4*)Wo + (size_t)i * 2;
            f32x4 a = p[0], c = p[1];
            u32* o = (u32*)(Wbf + (size_t)i * 8);
            o[0] = pk2(a.x, a.y); o[1] = pk2(a.z, a.w);
            o[2] = pk2(c.x, c.y); o[3] = pk2(c.z, c.w);
        }
        // We / Wd casts: 16384 units each (128 x 1024)
        if (gt < 16384) {
            const f32x4* p = (const f32x4*)We + (size_t)gt * 2;
            f32x4 a = p[0], c = p[1];
            u32* o = (u32*)(We_bf + (size_t)gt * 8);
            o[0] = pk2(a.x, a.y); o[1] = pk2(a.z, a.w);
            o[2] = pk2(c.x, c.y); o[3] = pk2(c.z, c.w);
            const f32x4* p2 = (const f32x4*)Wd + (size_t)gt * 2;
            f32x4 a2 = p2[0], c2 = p2[1];
            u32* o2 = (u32*)(Wd_bf + (size_t)gt * 8);
            o2[0] = pk2(a2.x, a2.y); o2[1] = pk2(a2.z, a2.w);
            o2[2] = pk2(c2.x, c2.y); o2[3] = pk2(c2.z, c2.w);
        }
        // dec W2 swizzled images: 4,194,304 u32 writes (4096 x 2048 bf16)
        for (int i = gt; i < 4194304; i += 32768) {
            int n = i >> 10, kp = i & 1023, k0 = kp << 1;
            int orig = (n & 3) * 1024 + (n >> 2);
            const float* s = (k0 < 1024) ? (dWhh + (size_t)orig * 1024 + k0)
                                         : (dWih + (size_t)orig * 1280 + 256 + (k0 - 1024));
            int g2 = n >> 5, r = n & 31;
            int byteoff = (k0 << 1) ^ ((r & 7) << 4);
            *(u32*)((char*)W2s + (size_t)g2 * 131072 + r * 4096 + byteoff) = pk2(s[0], s[1]);
        }
        return;
    }

    // ---------- sync encoder (R9) ----------
    int dir = blockIdx.x >> 6, g = blockIdx.x & 63;
    const char* wsrc = (const char*)(dir ? Wsb : Wsf) + (size_t)g * 32768;
#pragma unroll
    for (int it = 0; it < 8; ++it)
        GLL(wsrc + it * 4096 + tid * 16, smem + it * 4096 + tid * 16);
    __syncthreads();

    float* sacc = (float*)(smem + 32768);   // [4][32][33]
    u16* hst = (u16*)(smem + 49664);        // [32][8]
    const float* Gp = dir ? Gbp : Gfp;
    float* cB = cfb + dir * 16384;
    int lr = lane & 15, lk = (lane >> 4) << 3;
    int bb = tid & 31, jl = tid >> 5;
    int n0 = g * 32, j = g * 8 + jl;

    for (int s = 0; s < 64; ++s) {
        if (s) poll8(go8 + s * 128);
        int t = dir ? (63 - s) : s;
        f32x4 p4 = *(const f32x4*)(Gp + ((size_t)(t * 32 + bb)) * 2048 + n0 + (jl << 2));
        const u16* hA = henc + (size_t)s * 32768 + dir * 16384;
        s16x8 afr[8];
#pragma unroll
        for (int it = 0; it < 4; ++it) {
            int ke = q * 128 + it * 32 + lk;
            afr[2 * it]     = *(const s16x8*)(hA + lr * 512 + ke);
            afr[2 * it + 1] = *(const s16x8*)(hA + (lr + 16) * 512 + ke);
        }
        f32x4 acc00 = {}, acc01 = {}, acc10 = {}, acc11 = {};
#pragma unroll
        for (int it = 0; it < 4; ++it) {
            int ke = q * 128 + it * 32 + lk;
            int kb = ke << 1;
            s16x8 b0 = *(const s16x8*)(smem + lr * 1024 + (kb ^ ((lr & 7) << 4)));
            int r1 = lr + 16;
            s16x8 b1 = *(const s16x8*)(smem + r1 * 1024 + (kb ^ ((r1 & 7) << 4)));
            acc00 = MFMA(afr[2 * it], b0, acc00, 0, 0, 0);
            acc01 = MFMA(afr[2 * it], b1, acc01, 0, 0, 0);
            acc10 = MFMA(afr[2 * it + 1], b0, acc10, 0, 0, 0);
            acc11 = MFMA(afr[2 * it + 1], b1, acc11, 0, 0, 0);
        }
        int rw = (lane >> 4) << 2;
#pragma unroll
        for (int rr = 0; rr < 4; ++rr) {
            sacc[q * 1056 + (rw + rr) * 33 + lr]        = acc00[rr];
            sacc[q * 1056 + (rw + rr) * 33 + 16 + lr]   = acc01[rr];
            sacc[q * 1056 + (16 + rw + rr) * 33 + lr]      = acc10[rr];
            sacc[q * 1056 + (16 + rw + rr) * 33 + 16 + lr] = acc11[rr];
        }
        __syncthreads();
        {
            int c4 = jl << 2;
            float gi = 0, gf = 0, gg = 0, go2 = 0;
#pragma unroll
            for (int q2 = 0; q2 < 4; ++q2) {
                const float* sp = sacc + q2 * 1056 + bb * 33 + c4;
                gi += sp[0]; gf += sp[1]; gg += sp[2]; go2 += sp[3];
            }
            gi += p4.x; gf += p4.y; gg += p4.z; go2 += p4.w;
            float* cp = cB + bb * 512 + j;
            float cn = sigm_(gf) * cp[0] + sigm_(gi) * tanhf(gg);
            cp[0] = cn;
            float h = sigm_(go2) * tanhf(cn);
            u16 h16 = f2bf(h);
            encbf[((size_t)(bb * 64 + t)) * 1024 + dir * 512 + j] = h16;
            hst[bb * 8 + jl] = h16;
        }
        __syncthreads();
        if (tid < 128) {
            int bb2 = tid >> 2, p2 = tid & 3;
            u32 wv = (u32)hst[bb2 * 8 + 2 * p2] | ((u32)hst[bb2 * 8 + 2 * p2 + 1] << 16);
            ast32((u32*)(henc + (size_t)(s + 1) * 32768 + dir * 16384) + bb2 * 256 + g * 4 + p2, wv);
        }
        arrive8(cnt8 + (s + 1) * 128, go8 + (s + 1) * 128, blockIdx.x & 7, 16);
    }
}

// ---------------- decoder init ----------------
__global__ __launch_bounds__(256) void k_dec_init(
    const u16* __restrict__ henc, const float* __restrict__ cfb,
    u16* __restrict__ hcarr, float* __restrict__ cd)
{
    int idx = blockIdx.x * 256 + threadIdx.x;   // 0..32767
    int b = idx >> 10, j = idx & 1023;
    int dir = (j >> 9), jj = j & 511;
    hcarr[b * 2048 + j] = henc[(size_t)64 * 32768 + dir * 16384 + b * 512 + jj];
    cd[b * 1024 + j] = cfb[dir * 16384 + b * 512 + jj];
}

// ---------------- persistent decoder (R9 verbatim): split-line handoffs ----------------
// 160 blocks: 0..127 gate (W2 slice in LDS), 128..159 attn (enc rows in LDS).
__global__ __launch_bounds__(256, 1) void k_dec_persist(
    const u16* __restrict__ W2s, const u16* __restrict__ encbf,
    const float* __restrict__ Prep,
    const u16* __restrict__ Wd_bf, const float* __restrict__ bd,
    const float* __restrict__ eproj, const float* __restrict__ v_att,
    const float* __restrict__ bv,
    u16* __restrict__ hcarr, float* __restrict__ cd, u16* __restrict__ Abf,
    int* __restrict__ hCnt8, int* __restrict__ goH8,
    int* __restrict__ ctxCnt8, int* __restrict__ goCtx8)
{
    __shared__ __align__(16) char smem[148480];
    int blk = blockIdx.x, tid = threadIdx.x, lane = tid & 63, q = tid >> 6;
    bool isgate = blk < 128;
    {
        const char* src = isgate ? ((const char*)W2s + (size_t)blk * 131072)
                                 : ((const char*)encbf + (size_t)(blk - 128) * 131072);
#pragma unroll
        for (int it = 0; it < 32; ++it)
            GLL(src + it * 4096 + tid * 16, smem + it * 4096 + tid * 16);
    }
    __syncthreads();

    float* sacc = (float*)(smem + 131072);  // gates: [4][32][33]
    u16* hst    = (u16*)(smem + 147968);    // gates: [32][8]
    float* hsh  = (float*)(smem + 131072);  // attn: h f32 [1024]
    float* red  = (float*)(smem + 135168);  // attn: [256]
    float* dp   = (float*)(smem + 136192);  // attn: [128]
    float* sc   = (float*)(smem + 136704);  // attn: [64]

    int lr = lane & 15, lk = (lane >> 4) << 3;
    int bb = tid & 31, jl = tid >> 5;
    int n0 = blk * 32, j = blk * 8 + jl;
    int b = blk - 128;

    for (int t = 0; t < 64; ++t) {
        if (t) poll8(goH8 + t * 128);
        const u16* hcT = hcarr + (size_t)t * 65536;
        if (isgate) {
            f32x4 p4 = *(const f32x4*)(Prep + ((size_t)(t * 32 + bb)) * 4096 + n0 + (jl << 2));
            // ---- phase A: Whh · h_t (k in [0,1024)) ----
            s16x8 afr[16];
#pragma unroll
            for (int it = 0; it < 8; ++it) {
                int ke = q * 256 + it * 32 + lk;
                afr[2 * it]     = *(const s16x8*)(hcT + lr * 2048 + ke);
                afr[2 * it + 1] = *(const s16x8*)(hcT + (lr + 16) * 2048 + ke);
            }
            f32x4 acc00 = {}, acc01 = {}, acc10 = {}, acc11 = {};
#pragma unroll
            for (int it = 0; it < 8; ++it) {
                int ke = q * 256 + it * 32 + lk;
                int kb = ke << 1;
                s16x8 b0 = *(const s16x8*)(smem + lr * 4096 + (kb ^ ((lr & 7) << 4)));
                int r1 = lr + 16;
                s16x8 b1 = *(const s16x8*)(smem + r1 * 4096 + (kb ^ ((r1 & 7) << 4)));
                acc00 = MFMA(afr[2 * it], b0, acc00, 0, 0, 0);
                acc01 = MFMA(afr[2 * it], b1, acc01, 0, 0, 0);
                acc10 = MFMA(afr[2 * it + 1], b0, acc10, 0, 0, 0);
                acc11 = MFMA(afr[2 * it + 1], b1, acc11, 0, 0, 0);
            }
            // ---- wait for ctx_t ----
            poll8(goCtx8 + t * 128);
            // ---- phase B: Wctx · ctx_t (k in [1024,2048)) ----
#pragma unroll
            for (int it = 0; it < 8; ++it) {
                int ke = 1024 + q * 256 + it * 32 + lk;
                afr[2 * it]     = *(const s16x8*)(hcT + lr * 2048 + ke);
                afr[2 * it + 1] = *(const s16x8*)(hcT + (lr + 16) * 2048 + ke);
            }
#pragma unroll
            for (int it = 0; it < 8; ++it) {
                int ke = 1024 + q * 256 + it * 32 + lk;
                int kb = ke << 1;
                s16x8 b0 = *(const s16x8*)(smem + lr * 4096 + (kb ^ ((lr & 7) << 4)));
                int r1 = lr + 16;
                s16x8 b1 = *(const s16x8*)(smem + r1 * 4096 + (kb ^ ((r1 & 7) << 4)));
                acc00 = MFMA(afr[2 * it], b0, acc00, 0, 0, 0);
                acc01 = MFMA(afr[2 * it], b1, acc01, 0, 0, 0);
                acc10 = MFMA(afr[2 * it + 1], b0, acc10, 0, 0, 0);
                acc11 = MFMA(afr[2 * it + 1], b1, acc11, 0, 0, 0);
            }
            int rw = (lane >> 4) << 2;
#pragma unroll
            for (int rr = 0; rr < 4; ++rr) {
                sacc[q * 1056 + (rw + rr) * 33 + lr]        = acc00[rr];
                sacc[q * 1056 + (rw + rr) * 33 + 16 + lr]   = acc01[rr];
                sacc[q * 1056 + (16 + rw + rr) * 33 + lr]      = acc10[rr];
                sacc[q * 1056 + (16 + rw + rr) * 33 + 16 + lr] = acc11[rr];
            }
            __syncthreads();
            {
                int c4 = jl << 2;
                float gi = 0, gf = 0, gg = 0, go2 = 0;
#pragma unroll
                for (int q2 = 0; q2 < 4; ++q2) {
                    const float* sp = sacc + q2 * 1056 + bb * 33 + c4;
                    gi += sp[0]; gf += sp[1]; gg += sp[2]; go2 += sp[3];
                }
                gi += p4.x; gf += p4.y; gg += p4.z; go2 += p4.w;
                int ci = bb * 1024 + j;
                float cn = sigm_(gf) * cd[ci] + sigm_(gi) * tanhf(gg);
                cd[ci] = cn;
                float h = sigm_(go2) * tanhf(cn);
                u16 h16 = f2bf(h);
                Abf[((size_t)(t * 32 + bb)) * 2048 + j] = h16;
                hst[bb * 8 + jl] = h16;
            }
            __syncthreads();
            if (tid < 128) {
                int bb2 = tid >> 2, p2 = tid & 3;
                u32 wv = (u32)hst[bb2 * 8 + 2 * p2] | ((u32)hst[bb2 * 8 + 2 * p2 + 1] << 16);
                ast32((u32*)(hcarr + (size_t)(t + 1) * 65536) + bb2 * 1024 + blk * 4 + p2, wv);
            }
            arrive8(hCnt8 + (t + 1) * 128, goH8 + (t + 1) * 128, blk & 7, 16);
        } else {
            // ---- attention for batch row b ----
            {
                u16x4 hv = *(const u16x4*)(hcT + b * 2048 + (tid << 2));
                hsh[(tid << 2) + 0] = bf2f(hv.x);
                hsh[(tid << 2) + 1] = bf2f(hv.y);
                hsh[(tid << 2) + 2] = bf2f(hv.z);
                hsh[(tid << 2) + 3] = bf2f(hv.w);
            }
            __syncthreads();
            {
                int a = tid & 127, half = tid >> 7;
                const u16* wr = Wd_bf + ((size_t)a << 10) + (half << 9);
                const float* hh = hsh + (half << 9);
                float s0 = 0, s1 = 0, s2 = 0, s3 = 0;
#pragma unroll 4
                for (int k = 0; k < 512; k += 32) {
                    s16x8 w0 = *(const s16x8*)(wr + k);
                    s16x8 w1 = *(const s16x8*)(wr + k + 8);
                    s16x8 w2 = *(const s16x8*)(wr + k + 16);
                    s16x8 w3 = *(const s16x8*)(wr + k + 24);
#pragma unroll
                    for (int e = 0; e < 8; ++e) {
                        s0 += bf2f((u16)w0[e]) * hh[k + e];
                        s1 += bf2f((u16)w1[e]) * hh[k + 8 + e];
                        s2 += bf2f((u16)w2[e]) * hh[k + 16 + e];
                        s3 += bf2f((u16)w3[e]) * hh[k + 24 + e];
                    }
                }
                red[tid] = (s0 + s1) + (s2 + s3);
            }
            __syncthreads();
            if (tid < 128) dp[tid] = red[tid] + red[tid + 128] + bd[tid];
            __syncthreads();
            {
                int si = tid >> 2, qq = tid & 3;
                const float* ep = eproj + ((size_t)(b * 64 + si)) * 128 + qq * 32;
                float s = 0.0f;
#pragma unroll 8
                for (int a2 = 0; a2 < 32; ++a2)
                    s += v_att[qq * 32 + a2] * tanh_(dp[qq * 32 + a2] + ep[a2]);
                red[tid] = s;
            }
            __syncthreads();
            if (tid < 64) {
                float x = red[tid * 4] + red[tid * 4 + 1] + red[tid * 4 + 2] + red[tid * 4 + 3] + bv[0];
                float mx = x;
#pragma unroll
                for (int off = 32; off; off >>= 1) mx = fmaxf(mx, __shfl_xor(mx, off));
                float e = __expf(x - mx), ss = e;
#pragma unroll
                for (int off = 32; off; off >>= 1) ss += __shfl_xor(ss, off);
                sc[tid] = e / ss;
            }
            __syncthreads();
            u32 cw0, cw1;
            {
                const u16* eL = (const u16*)smem;
                int c0i = tid << 2;
                float c0 = 0, c1 = 0, c2 = 0, c3 = 0;
                for (int s2 = 0; s2 < 64; ++s2) {
                    float wgt = sc[s2];
                    u16x4 rp = *(const u16x4*)(eL + s2 * 1024 + c0i);
                    c0 += wgt * bf2f(rp.x); c1 += wgt * bf2f(rp.y);
                    c2 += wgt * bf2f(rp.z); c3 += wgt * bf2f(rp.w);
                }
                cw0 = pk2(c0, c1); cw1 = pk2(c2, c3);
                u32* hw = (u32*)hcT + b * 1024 + 512 + (tid << 1);
                ast32(hw, cw0); ast32(hw + 1, cw1);
            }
            arrive8(ctxCnt8 + t * 128, goCtx8 + t * 128, blk & 7, 4);
            {   // Abf ctx copy off the critical path
                u32* aw = (u32*)(Abf + ((size_t)(t * 32 + b)) * 2048 + 1024 + (tid << 2));
                aw[0] = cw0; aw[1] = cw1;
            }
        }
    }
}

// ---------------- host ----------------
extern "C" void kernel_launch(void* const* d_in, const int* in_sizes, int n_in,
                              void* d_out, int out_size, void* d_ws, size_t ws_size,
                              hipStream_t stream)
{
    (void)in_sizes; (void)n_in; (void)out_size; (void)ws_size;
    const int*   src     = (const int*)d_in[0];
    const int*   tgt     = (const int*)d_in[1];
    const float* enc_emb = (const float*)d_in[2];
    const float* eWih_f  = (const float*)d_in[3];
    const float* eWhh_f  = (const float*)d_in[4];
    const float* ebih_f  = (const float*)d_in[5];
    const float* ebhh_f  = (const float*)d_in[6];
    const float* eWih_b  = (const float*)d_in[7];
    const float* eWhh_b  = (const float*)d_in[8];
    const float* ebih_b  = (const float*)d_in[9];
    const float* ebhh_b  = (const float*)d_in[10];
    const float* dec_emb = (const float*)d_in[11];
    const float* Wd      = (const float*)d_in[12];
    const float* bd      = (const float*)d_in[13];
    const float* We      = (const float*)d_in[14];
    const float* be      = (const float*)d_in[15];
    const float* v_att   = (const float*)d_in[16];
    const float* bv      = (const float*)d_in[17];
    const float* dWih    = (const float*)d_in[18];
    const float* dWhh    = (const float*)d_in[19];
    const float* dbih    = (const float*)d_in[20];
    const float* dbhh    = (const float*)d_in[21];
    const float* Wo      = (const float*)d_in[22];
    const float* bo      = (const float*)d_in[23];
    float* out = (float*)d_out;

    char* wp = (char*)d_ws;
    auto alloc = [&](size_t nbytes) -> void* {
        void* p = (void*)wp;
        wp += (nbytes + 255) & ~(size_t)255;
        return p;
    };
    u16*   Xe_bf = (u16*)alloc(2048u * 256 * 2);
    u16*   Ed_bf = (u16*)alloc(2048u * 256 * 2);
    float* Gf_p  = (float*)alloc(2048u * 2048 * 4);
    float* Gb_p  = (float*)alloc(2048u * 2048 * 4);
    float* Pre_p = (float*)alloc(2048u * 4096 * 4);
    float* zr    = (float*)alloc(329728u);             // cfb | sync arrays
    float* cfb   = zr;                                 // 131072 B
    char*  sy    = (char*)zr + 131072;
    int*   cntE8 = (int*)(sy);                          // 65*512 B
    int*   goE8  = (int*)(sy + 33280);
    int*   hCnt8 = (int*)(sy + 66560);
    int*   goH8  = (int*)(sy + 99840);
    int*   ctxC8 = (int*)(sy + 133120);                 // 64*512 B
    int*   goX8  = (int*)(sy + 165888);
    u16*   henc  = (u16*)alloc(65u * 32768 * 2);       // per-step enc h
    u16*   hcarr = (u16*)alloc(65u * 65536 * 2);       // per-step dec h|ctx
    u16*   encbf = (u16*)alloc(2048u * 1024 * 2);
    float* eproj = (float*)alloc(2048u * 128 * 4);
    float* cd    = (float*)alloc(32768u * 4);
    u16*   Abf   = (u16*)alloc(2048u * 2048 * 2);
    u16*   Wbf   = (u16*)alloc(32000u * 2048 * 2);
    u16*   W2s   = (u16*)alloc(4096u * 2048 * 2);
    u16*   Wsf   = (u16*)alloc(2048u * 512 * 2);
    u16*   Wsb   = (u16*)alloc(2048u * 512 * 2);
    u16*   Wembf = (u16*)alloc(2048u * 256 * 2);
    u16*   Wembb = (u16*)alloc(2048u * 256 * 2);
    u16*   Wembd = (u16*)alloc(4096u * 256 * 2);
    u16*   We_bf = (u16*)alloc(128u * 1024 * 2);
    u16*   Wd_bf = (u16*)alloc(128u * 1024 * 2);

    // zero cfb + sync (329728 B = 82432 f32), henc step-0
    k_zero<<<322, 256, 0, stream>>>(zr, 82432);
    k_zero<<<64, 256, 0, stream>>>((float*)henc, 16384);

    // weight prep needed BEFORE encoder (rest is fused into encoder prep workers)
    k_prep_perm<<<512, 256, 0, stream>>>(eWih_f, Wembf, 512, 64, 256, 0, 131072);
    k_prep_perm<<<512, 256, 0, stream>>>(eWih_b, Wembb, 512, 64, 256, 0, 131072);
    k_prep_perm<<<1024, 256, 0, stream>>>(dWih, Wembd, 1024, 64, 1280, 0, 262144);
    k_prep_ws<<<2048, 256, 0, stream>>>(eWhh_f, Wsf);
    k_prep_ws<<<2048, 256, 0, stream>>>(eWhh_b, Wsb);

    k_embed_bf<<<512, 256, 0, stream>>>(src, enc_emb, Xe_bf);
    k_embed_bf<<<512, 256, 0, stream>>>(tgt, dec_emb, Ed_bf);

    // input projections (gate-interleaved outputs, biases folded)
    k_gemm_bf<<<256, 256, 0, stream>>>(Xe_bf, Wembf, 256, ebih_f, ebhh_f, 512,
                                       Gf_p, 2048, 16, 16, 0, 1, 0);
    k_gemm_bf<<<256, 256, 0, stream>>>(Xe_bf, Wembb, 256, ebih_b, ebhh_b, 512,
                                       Gb_p, 2048, 16, 16, 0, 1, 0);
    k_gemm_bf<<<512, 256, 0, stream>>>(Ed_bf, Wembd, 256, dbih, dbhh, 1024,
                                       Pre_p, 4096, 16, 32, 0, 1, 0);

    // persistent encoder (128 sync) + prep workers (128): Wo/We/Wd casts + W2s
    k_enc_persist<<<256, 256, 0, stream>>>(Wsf, Wsb, Gf_p, Gb_p, henc, cfb, encbf,
                                           cntE8, goE8,
                                           Wo, Wbf, We, We_bf, Wd, Wd_bf,
                                           dWhh, dWih, W2s);

    // enc_proj + decoder init
    k_gemm_bf<<<16, 256, 0, stream>>>(encbf, We_bf, 1024, be, nullptr, 0,
                                      eproj, 128, 16, 1, 0, 1, 0);
    k_dec_init<<<128, 256, 0, stream>>>(henc, cfb, hcarr, cd);

    // persistent decoder (R9, 160 blocks)
    k_dec_persist<<<160, 256, 0, stream>>>(W2s, encbf, Pre_p, Wd_bf, bd, eproj,
                                           v_att, bv, hcarr, cd, Abf,
                                           hCnt8, goH8, ctxC8, goX8);

    // standalone logits: [2048,2048] @ [32000,2048]^T, row remap, nontemporal stores
    k_gemm_bf<<<4000, 256, 0, stream>>>(Abf, Wbf, 2048, bo, nullptr, 0,
                                        out, 32000, 16, 250, 1, 1, 1);
}